// Round 4
// baseline (402.497 us; speedup 1.0000x reference)
//
#include <hip/hip_runtime.h>

#define HDIM 2048
#define HH (HDIM * HDIM)          // 4,194,304
#define NIDX 2000000
#define BINS 256
#define TL_BLOCKS 2048            // tabloss grid (partials count)
#define HP_BLOCKS 1024            // histpack grid (slab count)
#define SC_BLOCKS 2048            // scatter grid
#define RED_BLOCKS 96             // 96*256 = 24576 = 16 parts x 1536 bins

// workspace layout (bytes)
#define PART_OFF   0                       // double partials[TL_BLOCKS] = 16 KB
#define TAB_OFF    16384                   // float tab[3*BINS] = 3 KB
#define SLAB_OFF   32768                   // uint slab[HP_BLOCKS][6*BINS] = 6 MB
#define HISTR_OFF  8380416                 // uint histR[6*BINS] = 6 KB (memset start)
#define CNT_D_OFF  8388608                 // ushort cnt_d[HH] = 8 MB
#define CNT_R_OFF  16777216                // ushort cnt_r[HH] = 8 MB (ends 24 MB)
#define MEMSET_OFF  HISTR_OFF
#define MEMSET_BYTES (8192 + 4 * HH)       // histR pad + both uint16 count maps

// Node 1 (after memset): scatter sample counts into per-pixel uint16 count
// maps. Replaces the 4M random GATHERS (237MB fetch, 120us, latency-bound)
// with 4M fire-and-forget atomic scatters into 16MB of count lines.
// uint16 packing: +1 to low/high half via 32-bit atomicAdd of 1<<(16*(p&1));
// carries impossible (max multiplicity ~10 << 65536 for random indices).
__global__ __launch_bounds__(256) void scatter_kernel(
    const int* __restrict__ i0, const int* __restrict__ i1,
    const int* __restrict__ i2, const int* __restrict__ i3,
    unsigned* __restrict__ cntw_d, unsigned* __restrict__ cntw_r)
{
    const int stride = gridDim.x * 256;
    for (int q = blockIdx.x * 256 + threadIdx.x; q < NIDX / 4; q += stride) {
        const int4 a = ((const int4*)i0)[q];
        const int4 b = ((const int4*)i1)[q];
        const int4 c = ((const int4*)i2)[q];
        const int4 d = ((const int4*)i3)[q];
        const int pd[4] = {a.x * HDIM + b.x, a.y * HDIM + b.y, a.z * HDIM + b.z, a.w * HDIM + b.w};
        const int pr[4] = {c.x * HDIM + d.x, c.y * HDIM + d.y, c.z * HDIM + d.z, c.w * HDIM + d.w};
#pragma unroll
        for (int k = 0; k < 4; k++)
            atomicAdd(&cntw_d[pd[k] >> 1], 1u << ((pd[k] & 1) << 4));
#pragma unroll
        for (int k = 0; k < 4; k++)
            atomicAdd(&cntw_r[pr[k] >> 1], 1u << ((pr[k] & 1) << 4));
    }
}

// Node 2: STREAMING histogram — one pass over images, bins computed inline
// (identical math to the validated pack kernel), weighted by the count maps.
// No packed arrays, no gathers. Bin-0 (masked pixels) accumulates in
// registers (LDS same-address atomic hotspot avoidance, validated theory R8).
// Flush = non-atomic per-block slab store (no far atomics).
__global__ __launch_bounds__(256) void histpack_kernel(
    const float* __restrict__ ref, const float* __restrict__ tgt,
    const float* __restrict__ msrc, const float* __restrict__ mtar,
    const unsigned short* __restrict__ cnt_d, const unsigned short* __restrict__ cnt_r,
    unsigned* __restrict__ slab)
{
    __shared__ unsigned lhist[6 * BINS];
    for (int k = threadIdx.x; k < 6 * BINS; k += 256) lhist[k] = 0;
    __syncthreads();

    unsigned z[6] = {0, 0, 0, 0, 0, 0};   // bin-0 register accumulators (weighted)

    const int stride = gridDim.x * 256;
    for (int g = blockIdx.x * 256 + threadIdx.x; g < HH / 4; g += stride) {
        const int p = g * 4;
        const uint2 cdw = *(const uint2*)(cnt_d + p);
        const uint2 crw = *(const uint2*)(cnt_r + p);
        const unsigned cd[4] = {cdw.x & 0xFFFFu, cdw.x >> 16, cdw.y & 0xFFFFu, cdw.y >> 16};
        const unsigned cr[4] = {crw.x & 0xFFFFu, crw.x >> 16, crw.y & 0xFFFFu, crw.y >> 16};
        const float4 ms4 = *(const float4*)(msrc + p);
        const float4 mt4 = *(const float4*)(mtar + p);
        const float ms[4] = {ms4.x, ms4.y, ms4.z, ms4.w};
        const float mt[4] = {mt4.x, mt4.y, mt4.z, mt4.w};
#pragma unroll
        for (int c = 0; c < 3; c++) {
            const float4 rv = *(const float4*)(ref + c * HH + p);
            const float4 tv = *(const float4*)(tgt + c * HH + p);
            const float r[4] = {rv.x, rv.y, rv.z, rv.w};
            const float tt[4] = {tv.x, tv.y, tv.z, tv.w};
#pragma unroll
            for (int k = 0; k < 4; k++) {
                if (cd[k]) {
                    // reference op order: ((x+1)*0.5)*255, then * mask
                    const float vd = ((r[k] + 1.0f) * 0.5f) * 255.0f * ms[k];
                    const unsigned bd = (unsigned)(int)fminf(fmaxf(floorf(vd), 0.0f), 255.0f);
                    if (bd) atomicAdd(&lhist[c * BINS + bd], cd[k]); else z[c] += cd[k];
                }
                if (cr[k]) {
                    const float vr = ((tt[k] + 1.0f) * 0.5f) * 255.0f * mt[k];
                    const unsigned br = (unsigned)(int)fminf(fmaxf(floorf(vr), 0.0f), 255.0f);
                    if (br) atomicAdd(&lhist[(3 + c) * BINS + br], cr[k]); else z[3 + c] += cr[k];
                }
            }
        }
    }
#pragma unroll
    for (int c = 0; c < 6; c++)
        if (z[c]) atomicAdd(&lhist[c * BINS], z[c]);
    __syncthreads();
    unsigned* s = slab + blockIdx.x * (6 * BINS);
    for (int k = threadIdx.x; k < 6 * BINS; k += 256) s[k] = lhist[k];
}

// Node 3: deterministic slab reduction -> histR[1536]. 16 partial-sums per
// bin, folded with integer far atomics (24K atomics total, negligible).
__global__ __launch_bounds__(256) void reduce_kernel(
    const unsigned* __restrict__ slab, unsigned* __restrict__ histR)
{
    const int T    = blockIdx.x * 256 + threadIdx.x;   // 0..24575
    const int bin  = T % (6 * BINS);
    const int part = T / (6 * BINS);                   // 0..15
    const int b0   = part * (HP_BLOCKS / 16);          // 64 slabs each
    unsigned s = 0;
#pragma unroll 8
    for (int b = 0; b < HP_BLOCKS / 16; b++)
        s += slab[(b0 + b) * (6 * BINS) + bin];
    if (s) atomicAdd(&histR[bin], s);
}

// Node 4: transfer table (1 block). Validated logic: exact int scan ->
// single-rounding divide -> bsearch. Input is now the reduced histR.
__global__ __launch_bounds__(256) void table_kernel(
    const unsigned* __restrict__ histR, float* __restrict__ tabg)
{
    __shared__ float    cdf[6 * BINS];
    __shared__ unsigned wsum[4];

    const int t    = threadIdx.x;
    const int lane = t & 63;
    const int wid  = t >> 6;

    for (int ch = 0; ch < 6; ch++) {
        unsigned x = histR[ch * BINS + t];
#pragma unroll
        for (int d = 1; d < 64; d <<= 1) {
            const unsigned y = __shfl_up(x, d, 64);
            if (lane >= d) x += y;
        }
        if (lane == 63) wsum[wid] = x;
        __syncthreads();
        unsigned prefix = 0;
        for (int w = 0; w < wid; w++) prefix += wsum[w];
        x += prefix;
        cdf[ch * BINS + t] = (float)x / 2000000.0f;   // exact int < 2^24, single rounding
        __syncthreads();
    }
    for (int c = 0; c < 3; c++) {
        float o;
        if (t == 0)             o = 0.0f;
        else if (t == BINS - 1) o = 255.0f;
        else {
            const float v = cdf[c * BINS + t];
            const float* arr = cdf + (3 + c) * BINS;
            int lo = 0, hi = 256;   // lower_bound: first k with arr[k] >= v
            while (lo < hi) { const int mid = (lo + hi) >> 1; if (arr[mid] < v) lo = mid + 1; else hi = mid; }
            const int J0 = ((lo > 1) ? lo : 1) - 1;
            int lo2 = 0, hi2 = 256; // upper_bound: first k with arr[k] > v
            while (lo2 < hi2) { const int mid = (lo2 + hi2) >> 1; if (arr[mid] <= v) lo2 = mid + 1; else hi2 = mid; }
            const int J1 = ((lo2 - 1) < 254 ? (lo2 - 1) : 254);
            const bool found = (lo2 >= 1) && (J0 <= J1);
            o = found ? (float)(J0 + 1) : (float)t;
        }
        tabg[c * BINS + t] = o;
    }
}

// Node 5: streaming loss. "sampled" = cnt_d > 0 (identical semantics to the
// old bitmap). Plain per-block partial store; stream-order visibility.
__global__ __launch_bounds__(256) void tabloss_kernel(
    const float* __restrict__ inp, const float* __restrict__ ref,
    const float* __restrict__ msrc, const float* __restrict__ tabg,
    const unsigned short* __restrict__ cnt_d, double* __restrict__ partials)
{
    __shared__ float  tab[3 * BINS];
    __shared__ double red[256];

    const int t = threadIdx.x;
    for (int k = t; k < 3 * BINS; k += 256) tab[k] = tabg[k];
    __syncthreads();

    double local = 0.0;
    const int stride = gridDim.x * 256;
    for (int g = blockIdx.x * 256 + t; g < HH / 4; g += stride) {
        const int p = g * 4;
        const float4 mv = *(const float4*)(msrc + p);
        const uint2 cdw = *(const uint2*)(cnt_d + p);
        const unsigned samp[4] = {cdw.x & 0xFFFFu, cdw.x >> 16, cdw.y & 0xFFFFu, cdw.y >> 16};
        const float m[4] = {mv.x, mv.y, mv.z, mv.w};
#pragma unroll
        for (int c = 0; c < 3; c++) {
            const float4 rv = *(const float4*)(ref + c * HH + p);
            const float4 iv = *(const float4*)(inp + c * HH + p);
            const float r[4] = {rv.x, rv.y, rv.z, rv.w};
            const float x4[4] = {iv.x, iv.y, iv.z, iv.w};
            float s = 0.0f;
#pragma unroll
            for (int k = 0; k < 4; k++) {
                const float mm = m[k];
                const float refm = ((r[k] + 1.0f) * 0.5f) * 255.0f * mm;   // ref_masked
                const float inpm = ((x4[k] + 1.0f) * 0.5f) * 255.0f * mm;  // input_masked
                float matchv;
                if (samp[k]) {
                    const int bidx = (int)fminf(fmaxf(refm, 0.0f), 255.0f); // clip-then-trunc
                    matchv = tab[c * BINS + bidx];
                } else {
                    matchv = refm;
                }
                const float dd = inpm - matchv * mm;
                s += dd * dd;
            }
            local += (double)s;
        }
    }
    red[t] = local;
    __syncthreads();
    for (int s2 = 128; s2 > 0; s2 >>= 1) {
        if (t < s2) red[t] += red[t + s2];
        __syncthreads();
    }
    if (t == 0) partials[blockIdx.x] = red[0];
}

// Node 6: single-block finalize.
__global__ __launch_bounds__(256) void finalize_kernel(
    const double* __restrict__ partials, float* __restrict__ out)
{
    const int t = threadIdx.x;
    double s = 0.0;
    for (int k = t; k < TL_BLOCKS; k += 256) s += partials[k];
    __shared__ double red[256];
    red[t] = s;
    __syncthreads();
    for (int s2 = 128; s2 > 0; s2 >>= 1) {
        if (t < s2) red[t] += red[t + s2];
        __syncthreads();
    }
    if (t == 0) out[0] = (float)(red[0] / (double)(3 * HH));
}

extern "C" void kernel_launch(void* const* d_in, const int* in_sizes, int n_in,
                              void* d_out, int out_size, void* d_ws, size_t ws_size,
                              hipStream_t stream)
{
    const float* input_data  = (const float*)d_in[0];
    const float* target_data = (const float*)d_in[1];
    const float* mask_src    = (const float*)d_in[2];
    const float* mask_tar    = (const float*)d_in[3];
    const int*   i0          = (const int*)d_in[4];
    const int*   i1          = (const int*)d_in[5];
    const int*   i2          = (const int*)d_in[6];
    const int*   i3          = (const int*)d_in[7];
    const float* ref_data    = (const float*)d_in[8];
    float* out = (float*)d_out;

    char* ws = (char*)d_ws;
    double*         partials = (double*)(ws + PART_OFF);
    float*          tabg     = (float*)(ws + TAB_OFF);
    unsigned*       slab     = (unsigned*)(ws + SLAB_OFF);
    unsigned*       histR    = (unsigned*)(ws + HISTR_OFF);
    unsigned*       cntw_d   = (unsigned*)(ws + CNT_D_OFF);
    unsigned*       cntw_r   = (unsigned*)(ws + CNT_R_OFF);
    const unsigned short* cnt_d = (const unsigned short*)(ws + CNT_D_OFF);
    const unsigned short* cnt_r = (const unsigned short*)(ws + CNT_R_OFF);

    hipMemsetAsync(ws + MEMSET_OFF, 0, MEMSET_BYTES, stream);
    scatter_kernel<<<SC_BLOCKS, 256, 0, stream>>>(i0, i1, i2, i3, cntw_d, cntw_r);
    histpack_kernel<<<HP_BLOCKS, 256, 0, stream>>>(ref_data, target_data, mask_src, mask_tar,
                                                   cnt_d, cnt_r, slab);
    reduce_kernel<<<RED_BLOCKS, 256, 0, stream>>>(slab, histR);
    table_kernel<<<1, 256, 0, stream>>>(histR, tabg);
    tabloss_kernel<<<TL_BLOCKS, 256, 0, stream>>>(input_data, ref_data, mask_src, tabg,
                                                  cnt_d, partials);
    finalize_kernel<<<1, 256, 0, stream>>>(partials, out);
}

// Round 5
// 346.926 us; speedup vs baseline: 1.1602x; 1.1602x over previous
//
#include <hip/hip_runtime.h>

#define HDIM 2048
#define HH (HDIM * HDIM)          // 4,194,304
#define NIDX 2000000
#define BINS 256
#define NCOPY 16
#define TL_BLOCKS 2048            // tabloss grid (partials count)
#define HIST_BLOCKS 2048          // R5: full occupancy for gather MLP (was 512)

// workspace layout (bytes) — identical 33 MiB footprint to the proven R3 run
#define PART_OFF     0                      // double partials[TL_BLOCKS] = 16 KB
#define TAB_OFF      16384                  // float tab[3*BINS] = 3 KB
#define HIST_OFF     20480                  // uint hist[NCOPY][6][256] = 96 KB
#define PACKED_D_OFF 1048576                // uint packed_d[HH] = 16 MB (byte3 = sampled flag)
#define PACKED_R_OFF 17825792               // uint packed_r[HH] = 16 MB

// Node 1: zero hist + pack 3 channel bins (mask folded: v*0 -> bin 0)
// into bits 0..23 of one uint per pixel. Byte 3 left ZERO (sampled flag).
__global__ __launch_bounds__(256) void pack_kernel(
    const float* __restrict__ ref, const float* __restrict__ tgt,
    const float* __restrict__ msrc, const float* __restrict__ mtar,
    unsigned* __restrict__ packed_d, unsigned* __restrict__ packed_r,
    unsigned* __restrict__ hist)
{
    const int gtid = blockIdx.x * 256 + threadIdx.x;
    const int stride = gridDim.x * 256;

    for (int k = gtid; k < NCOPY * 6 * BINS; k += stride) hist[k] = 0;

    for (int g = gtid; g < HH / 4; g += stride) {
        const int p = g * 4;
        const float4 ms4 = *(const float4*)(msrc + p);
        const float4 mt4 = *(const float4*)(mtar + p);
        const float ms[4] = {ms4.x, ms4.y, ms4.z, ms4.w};
        const float mt[4] = {mt4.x, mt4.y, mt4.z, mt4.w};
        unsigned od[4] = {0, 0, 0, 0}, orr[4] = {0, 0, 0, 0};
#pragma unroll
        for (int c = 0; c < 3; c++) {
            const float4 rv = *(const float4*)(ref + c * HH + p);
            const float4 tv = *(const float4*)(tgt + c * HH + p);
            const float r[4] = {rv.x, rv.y, rv.z, rv.w};
            const float tt[4] = {tv.x, tv.y, tv.z, tv.w};
#pragma unroll
            for (int k = 0; k < 4; k++) {
                // reference op order: ((x+1)*0.5)*255, then * mask
                const float vd = ((r[k] + 1.0f) * 0.5f) * 255.0f * ms[k];
                const float vr = ((tt[k] + 1.0f) * 0.5f) * 255.0f * mt[k];
                const unsigned bd = (unsigned)(int)fminf(fmaxf(floorf(vd), 0.0f), 255.0f);
                const unsigned br = (unsigned)(int)fminf(fmaxf(floorf(vr), 0.0f), 255.0f);
                od[k]  |= bd << (8 * c);
                orr[k] |= br << (8 * c);
            }
        }
        *(uint4*)(packed_d + p) = make_uint4(od[0], od[1], od[2], od[3]);
        *(uint4*)(packed_r + p) = make_uint4(orr[0], orr[1], orr[2], orr[3]);
    }
}

// Node 2: gather histogram. R5: 2048 blocks (full occupancy — R3's 512-block
// version measured 18.7% occupancy and was gather-latency/MLP-bound at
// 2.59 TB/s). Sampled flag = PLAIN byte store into packed_d byte 3
// (benign same-value race; replaces 2M atomicOr whose device-scope
// write-through was 64 MB of HBM writes — R3/R4 counter evidence).
// Bin-0 increments stay in registers (masked pixels fold to bin 0 — avoids
// the ~32-way same-address LDS-atomic serialization). Flush = burst
// atomicAdd to 16 hist copies (hot-region atomics merge in L2 — R3 evidence).
__global__ __launch_bounds__(256) void hist_kernel(
    unsigned* __restrict__ packed_d, const unsigned* __restrict__ packed_r,
    const int* __restrict__ i0, const int* __restrict__ i1,
    const int* __restrict__ i2, const int* __restrict__ i3,
    unsigned* __restrict__ hist)
{
    __shared__ unsigned lhist[6 * BINS];
    for (int k = threadIdx.x; k < 6 * BINS; k += 256) lhist[k] = 0;
    __syncthreads();

    unsigned z0 = 0, z1 = 0, z2 = 0, z3 = 0, z4 = 0, z5 = 0;  // bin-0 counts
    unsigned char* sampled = (unsigned char*)packed_d;

    const int stride = gridDim.x * 256;
    for (int q = blockIdx.x * 256 + threadIdx.x; q < NIDX / 4; q += stride) {
        const int4 a = ((const int4*)i0)[q];
        const int4 b = ((const int4*)i1)[q];
        const int4 c = ((const int4*)i2)[q];
        const int4 d = ((const int4*)i3)[q];
        const int pd[4] = {a.x * HDIM + b.x, a.y * HDIM + b.y, a.z * HDIM + b.z, a.w * HDIM + b.w};
        const int pr[4] = {c.x * HDIM + d.x, c.y * HDIM + d.y, c.z * HDIM + d.z, c.w * HDIM + d.w};
        unsigned wd[4], wr[4];
#pragma unroll
        for (int k = 0; k < 4; k++) wd[k] = packed_d[pd[k]];
#pragma unroll
        for (int k = 0; k < 4; k++) wr[k] = packed_r[pr[k]];
#pragma unroll
        for (int k = 0; k < 4; k++) sampled[pd[k] * 4 + 3] = 1;   // plain store, benign race
#pragma unroll
        for (int k = 0; k < 4; k++) {
            const unsigned d0 =  wd[k]        & 255u;
            const unsigned d1 = (wd[k] >> 8 ) & 255u;
            const unsigned d2 = (wd[k] >> 16) & 255u;
            const unsigned r0 =  wr[k]        & 255u;
            const unsigned r1 = (wr[k] >> 8 ) & 255u;
            const unsigned r2 = (wr[k] >> 16) & 255u;
            if (d0) atomicAdd(&lhist[           d0], 1u); else z0++;
            if (d1) atomicAdd(&lhist[1 * BINS + d1], 1u); else z1++;
            if (d2) atomicAdd(&lhist[2 * BINS + d2], 1u); else z2++;
            if (r0) atomicAdd(&lhist[3 * BINS + r0], 1u); else z3++;
            if (r1) atomicAdd(&lhist[4 * BINS + r1], 1u); else z4++;
            if (r2) atomicAdd(&lhist[5 * BINS + r2], 1u); else z5++;
        }
    }
    if (z0) atomicAdd(&lhist[0 * BINS], z0);
    if (z1) atomicAdd(&lhist[1 * BINS], z1);
    if (z2) atomicAdd(&lhist[2 * BINS], z2);
    if (z3) atomicAdd(&lhist[3 * BINS], z3);
    if (z4) atomicAdd(&lhist[4 * BINS], z4);
    if (z5) atomicAdd(&lhist[5 * BINS], z5);
    __syncthreads();
    unsigned* h = hist + (blockIdx.x & (NCOPY - 1)) * (6 * BINS);
    for (int k = threadIdx.x; k < 6 * BINS; k += 256) {
        const unsigned v = lhist[k];
        if (v) atomicAdd(&h[k], v);
    }
}

// Node 3: transfer table computed ONCE (1 block). Validated logic: exact int
// scan -> single-rounding divide -> bsearch. Sums the 16 hist copies.
__global__ __launch_bounds__(256) void table_kernel(
    const unsigned* __restrict__ hist, float* __restrict__ tabg)
{
    __shared__ float    cdf[6 * BINS];
    __shared__ unsigned wsum[4];

    const int t    = threadIdx.x;
    const int lane = t & 63;
    const int wid  = t >> 6;

    for (int ch = 0; ch < 6; ch++) {
        unsigned x = 0;
#pragma unroll
        for (int cp = 0; cp < NCOPY; cp++) x += hist[cp * (6 * BINS) + ch * BINS + t];
#pragma unroll
        for (int d = 1; d < 64; d <<= 1) {
            const unsigned y = __shfl_up(x, d, 64);
            if (lane >= d) x += y;
        }
        if (lane == 63) wsum[wid] = x;
        __syncthreads();
        unsigned prefix = 0;
        for (int w = 0; w < wid; w++) prefix += wsum[w];
        x += prefix;
        cdf[ch * BINS + t] = (float)x / 2000000.0f;   // exact int < 2^24, single rounding
        __syncthreads();
    }
    for (int c = 0; c < 3; c++) {
        float o;
        if (t == 0)             o = 0.0f;
        else if (t == BINS - 1) o = 255.0f;
        else {
            const float v = cdf[c * BINS + t];
            const float* arr = cdf + (3 + c) * BINS;
            int lo = 0, hi = 256;   // lower_bound: first k with arr[k] >= v
            while (lo < hi) { const int mid = (lo + hi) >> 1; if (arr[mid] < v) lo = mid + 1; else hi = mid; }
            const int J0 = ((lo > 1) ? lo : 1) - 1;
            int lo2 = 0, hi2 = 256; // upper_bound: first k with arr[k] > v
            while (lo2 < hi2) { const int mid = (lo2 + hi2) >> 1; if (arr[mid] <= v) lo2 = mid + 1; else hi2 = mid; }
            const int J1 = ((lo2 - 1) < 254 ? (lo2 - 1) : 254);
            const bool found = (lo2 >= 1) && (J0 <= J1);
            o = found ? (float)(J0 + 1) : (float)t;
        }
        tabg[c * BINS + t] = o;
    }
}

// Node 4: streaming loss. Sampled flag read from packed_d byte 3 (coalesced
// uint4 loads). Plain per-block partial store; stream-order visibility.
__global__ __launch_bounds__(256) void tabloss_kernel(
    const float* __restrict__ inp, const float* __restrict__ ref,
    const float* __restrict__ msrc, const float* __restrict__ tabg,
    const unsigned* __restrict__ packed_d, double* __restrict__ partials)
{
    __shared__ float  tab[3 * BINS];
    __shared__ double red[256];

    const int t = threadIdx.x;
    for (int k = t; k < 3 * BINS; k += 256) tab[k] = tabg[k];
    __syncthreads();

    double local = 0.0;
    const int stride = gridDim.x * 256;
    for (int g = blockIdx.x * 256 + t; g < HH / 4; g += stride) {
        const int p = g * 4;
        const float4 mv = *(const float4*)(msrc + p);
        const uint4 pw = *(const uint4*)(packed_d + p);
        const unsigned samp[4] = {pw.x >> 24, pw.y >> 24, pw.z >> 24, pw.w >> 24};
        const float m[4] = {mv.x, mv.y, mv.z, mv.w};
#pragma unroll
        for (int c = 0; c < 3; c++) {
            const float4 rv = *(const float4*)(ref + c * HH + p);
            const float4 iv = *(const float4*)(inp + c * HH + p);
            const float r[4] = {rv.x, rv.y, rv.z, rv.w};
            const float x4[4] = {iv.x, iv.y, iv.z, iv.w};
            float s = 0.0f;
#pragma unroll
            for (int k = 0; k < 4; k++) {
                const float mm = m[k];
                const float refm = ((r[k] + 1.0f) * 0.5f) * 255.0f * mm;   // ref_masked
                const float inpm = ((x4[k] + 1.0f) * 0.5f) * 255.0f * mm;  // input_masked
                float matchv;
                if (samp[k]) {
                    const int bidx = (int)fminf(fmaxf(refm, 0.0f), 255.0f); // clip-then-trunc
                    matchv = tab[c * BINS + bidx];
                } else {
                    matchv = refm;
                }
                const float dd = inpm - matchv * mm;
                s += dd * dd;
            }
            local += (double)s;
        }
    }
    red[t] = local;
    __syncthreads();
    for (int s2 = 128; s2 > 0; s2 >>= 1) {
        if (t < s2) red[t] += red[t + s2];
        __syncthreads();
    }
    if (t == 0) partials[blockIdx.x] = red[0];
}

// Node 5: single-block finalize (plain loads; stream order guarantees visibility).
__global__ __launch_bounds__(256) void finalize_kernel(
    const double* __restrict__ partials, float* __restrict__ out)
{
    const int t = threadIdx.x;
    double s = 0.0;
    for (int k = t; k < TL_BLOCKS; k += 256) s += partials[k];
    __shared__ double red[256];
    red[t] = s;
    __syncthreads();
    for (int s2 = 128; s2 > 0; s2 >>= 1) {
        if (t < s2) red[t] += red[t + s2];
        __syncthreads();
    }
    if (t == 0) out[0] = (float)(red[0] / (double)(3 * HH));
}

extern "C" void kernel_launch(void* const* d_in, const int* in_sizes, int n_in,
                              void* d_out, int out_size, void* d_ws, size_t ws_size,
                              hipStream_t stream)
{
    const float* input_data  = (const float*)d_in[0];
    const float* target_data = (const float*)d_in[1];
    const float* mask_src    = (const float*)d_in[2];
    const float* mask_tar    = (const float*)d_in[3];
    const int*   i0          = (const int*)d_in[4];
    const int*   i1          = (const int*)d_in[5];
    const int*   i2          = (const int*)d_in[6];
    const int*   i3          = (const int*)d_in[7];
    const float* ref_data    = (const float*)d_in[8];
    float* out = (float*)d_out;

    char* ws = (char*)d_ws;
    double*   partials = (double*)(ws + PART_OFF);
    float*    tabg     = (float*)(ws + TAB_OFF);
    unsigned* hist     = (unsigned*)(ws + HIST_OFF);
    unsigned* packed_d = (unsigned*)(ws + PACKED_D_OFF);
    unsigned* packed_r = (unsigned*)(ws + PACKED_R_OFF);

    pack_kernel<<<2048, 256, 0, stream>>>(ref_data, target_data, mask_src, mask_tar,
                                          packed_d, packed_r, hist);
    hist_kernel<<<HIST_BLOCKS, 256, 0, stream>>>(packed_d, packed_r, i0, i1, i2, i3, hist);
    table_kernel<<<1, 256, 0, stream>>>(hist, tabg);
    tabloss_kernel<<<TL_BLOCKS, 256, 0, stream>>>(input_data, ref_data, mask_src, tabg,
                                                  packed_d, partials);
    finalize_kernel<<<1, 256, 0, stream>>>(partials, out);
}